// Round 4
// baseline (407.590 us; speedup 1.0000x reference)
//
#include <hip/hip_runtime.h>

typedef float f32x4 __attribute__((ext_vector_type(4)));

// y[b,:] = x[b,:] - (2 * dot(x[b],v) / ||v||^2) * v
// D = 128 floats/row; 32 lanes x float4 = one row. 8 rows per group-iteration.
__global__ __launch_bounds__(256) void hh_kernel(const float* __restrict__ x,
                                                 const float* __restrict__ v,
                                                 float* __restrict__ y,
                                                 int nrows) {
    const int tid = threadIdx.x;
    const int c = tid & 31;     // float4 index within the row
    const int rg = tid >> 5;    // row-group within block (0..7)

    const f32x4 v4 = reinterpret_cast<const f32x4*>(v)[c];

    // ||v||^2 : butterfly within the 32-lane group (masks <=16 stay in-group)
    float p = v4.x * v4.x + v4.y * v4.y + v4.z * v4.z + v4.w * v4.w;
#pragma unroll
    for (int m = 16; m >= 1; m >>= 1) p += __shfl_xor(p, m, 64);
    const float scale = 2.0f / p;

    const int n_groups = gridDim.x * 8;
    const int n_chunks = nrows >> 3;  // chunks of 8 consecutive rows

    for (int chunk = blockIdx.x * 8 + rg; chunk < n_chunks; chunk += n_groups) {
        const f32x4* xp = reinterpret_cast<const f32x4*>(x + (size_t)chunk * 1024) + c;
        f32x4* yp = reinterpret_cast<f32x4*>(y + (size_t)chunk * 1024) + c;

        f32x4 a[8];
#pragma unroll
        for (int r = 0; r < 8; ++r) a[r] = __builtin_nontemporal_load(xp + r * 32);

        float d[8];
#pragma unroll
        for (int r = 0; r < 8; ++r)
            d[r] = a[r].x * v4.x + a[r].y * v4.y + a[r].z * v4.z + a[r].w * v4.w;

#pragma unroll
        for (int m = 16; m >= 1; m >>= 1) {
#pragma unroll
            for (int r = 0; r < 8; ++r) d[r] += __shfl_xor(d[r], m, 64);
        }

#pragma unroll
        for (int r = 0; r < 8; ++r) {
            const float s = scale * d[r];
            f32x4 o;
            o.x = a[r].x - s * v4.x;
            o.y = a[r].y - s * v4.y;
            o.z = a[r].z - s * v4.z;
            o.w = a[r].w - s * v4.w;
            __builtin_nontemporal_store(o, yp + r * 32);
        }
    }

    // tail rows if nrows % 8 != 0 (not hit for B = 2^21, kept for safety)
    if (blockIdx.x == 0 && rg == 0) {
        for (int row = n_chunks << 3; row < nrows; ++row) {
            const f32x4 a = reinterpret_cast<const f32x4*>(x + (size_t)row * 128)[c];
            float d = a.x * v4.x + a.y * v4.y + a.z * v4.z + a.w * v4.w;
#pragma unroll
            for (int m = 16; m >= 1; m >>= 1) d += __shfl_xor(d, m, 64);
            const float s = scale * d;
            f32x4 o;
            o.x = a.x - s * v4.x; o.y = a.y - s * v4.y; o.z = a.z - s * v4.z; o.w = a.w - s * v4.w;
            reinterpret_cast<f32x4*>(y + (size_t)row * 128)[c] = o;
        }
    }

    // second tuple output: scalar 0 after y
    if (blockIdx.x == 0 && tid == 0) y[(size_t)nrows * 128] = 0.0f;
}

extern "C" void kernel_launch(void* const* d_in, const int* in_sizes, int n_in,
                              void* d_out, int out_size, void* d_ws, size_t ws_size,
                              hipStream_t stream) {
    const float* x = (const float*)d_in[0];
    const float* v = (const float*)d_in[1];
    float* y = (float*)d_out;
    const int nrows = in_sizes[0] / 128;

    const int block = 256;
    const int groups_per_block = block / 32;
    const int n_chunks = nrows / 8;
    int grid = (n_chunks + groups_per_block - 1) / groups_per_block;
    if (grid > 2048) grid = 2048;
    if (grid < 1) grid = 1;

    hh_kernel<<<grid, block, 0, stream>>>(x, v, y, nrows);
}

// Round 5
// 383.878 us; speedup vs baseline: 1.0618x; 1.0618x over previous
//
#include <hip/hip_runtime.h>

typedef float f32x4 __attribute__((ext_vector_type(4)));

// DPP-based add with compile-time ctrl (row_mask=0xF, bank_mask=0xF, bound_ctrl=1)
template<int CTRL>
__device__ __forceinline__ float dpp_add(float x) {
    int y = __builtin_amdgcn_update_dpp(0, __float_as_int(x), CTRL, 0xF, 0xF, true);
    return x + __int_as_float(y);
}

// Sum across a 16-lane group, result in all 16 lanes. Pure VALU (no DS pipe).
__device__ __forceinline__ float reduce16(float x) {
    x = dpp_add<0xB1>(x);   // quad_perm [1,0,3,2] : pair xor-1
    x = dpp_add<0x4E>(x);   // quad_perm [2,3,0,1] : pair xor-2
    x = dpp_add<0x141>(x);  // row_half_mirror     : pair across quads (within 8)
    x = dpp_add<0x140>(x);  // row_mirror          : pair across halves (within 16)
    return x;
}

__device__ __forceinline__ float dot4(f32x4 a, f32x4 b) {
    return a.x * b.x + a.y * b.y + a.z * b.z + a.w * b.w;
}

// y[b,:] = x[b,:] - (2 * dot(x[b],v) / ||v||^2) * v
// D = 128 floats/row. 16 lanes per row, 2 float4/lane; 2 rows per group-iter.
__global__ __launch_bounds__(256) void hh_kernel(const float* __restrict__ x,
                                                 const float* __restrict__ v,
                                                 float* __restrict__ y,
                                                 int nrows) {
    const int tid = threadIdx.x;
    const int c = tid & 15;   // float4 slot within row-half
    const int g = tid >> 4;   // 16-lane group within block (0..15)

    const f32x4* vv = reinterpret_cast<const f32x4*>(v);
    const f32x4 vA = vv[c];
    const f32x4 vB = vv[c + 16];

    const float p = reduce16(dot4(vA, vA) + dot4(vB, vB));
    const float scale = 2.0f / p;

    const int n_groups = gridDim.x * 16;
    const int n_chunks = nrows >> 1;  // chunks of 2 consecutive rows

    for (int chunk = blockIdx.x * 16 + g; chunk < n_chunks; chunk += n_groups) {
        const f32x4* xp = reinterpret_cast<const f32x4*>(x + (size_t)chunk * 256);
        f32x4* yp = reinterpret_cast<f32x4*>(y + (size_t)chunk * 256);

        const f32x4 a0A = __builtin_nontemporal_load(xp + c);
        const f32x4 a0B = __builtin_nontemporal_load(xp + c + 16);
        const f32x4 a1A = __builtin_nontemporal_load(xp + c + 32);
        const f32x4 a1B = __builtin_nontemporal_load(xp + c + 48);

        float d0 = dot4(a0A, vA) + dot4(a0B, vB);
        float d1 = dot4(a1A, vA) + dot4(a1B, vB);
        d0 = reduce16(d0);
        d1 = reduce16(d1);
        const float s0 = scale * d0;
        const float s1 = scale * d1;

        f32x4 o;
        o.x = a0A.x - s0 * vA.x; o.y = a0A.y - s0 * vA.y; o.z = a0A.z - s0 * vA.z; o.w = a0A.w - s0 * vA.w;
        __builtin_nontemporal_store(o, yp + c);
        o.x = a0B.x - s0 * vB.x; o.y = a0B.y - s0 * vB.y; o.z = a0B.z - s0 * vB.z; o.w = a0B.w - s0 * vB.w;
        __builtin_nontemporal_store(o, yp + c + 16);
        o.x = a1A.x - s1 * vA.x; o.y = a1A.y - s1 * vA.y; o.z = a1A.z - s1 * vA.z; o.w = a1A.w - s1 * vA.w;
        __builtin_nontemporal_store(o, yp + c + 32);
        o.x = a1B.x - s1 * vB.x; o.y = a1B.y - s1 * vB.y; o.z = a1B.z - s1 * vB.z; o.w = a1B.w - s1 * vB.w;
        __builtin_nontemporal_store(o, yp + c + 48);
    }

    // tail row if nrows is odd (not hit for B = 2^21, kept for safety)
    if (blockIdx.x == 0 && g == 0) {
        for (int row = n_chunks << 1; row < nrows; ++row) {
            const f32x4* xp = reinterpret_cast<const f32x4*>(x + (size_t)row * 128);
            f32x4* yp = reinterpret_cast<f32x4*>(y + (size_t)row * 128);
            const f32x4 aA = xp[c];
            const f32x4 aB = xp[c + 16];
            const float s = scale * reduce16(dot4(aA, vA) + dot4(aB, vB));
            f32x4 o;
            o.x = aA.x - s * vA.x; o.y = aA.y - s * vA.y; o.z = aA.z - s * vA.z; o.w = aA.w - s * vA.w;
            yp[c] = o;
            o.x = aB.x - s * vB.x; o.y = aB.y - s * vB.y; o.z = aB.z - s * vB.z; o.w = aB.w - s * vB.w;
            yp[c + 16] = o;
        }
    }

    // second tuple output: scalar 0 after y
    if (blockIdx.x == 0 && tid == 0) y[(size_t)nrows * 128] = 0.0f;
}

extern "C" void kernel_launch(void* const* d_in, const int* in_sizes, int n_in,
                              void* d_out, int out_size, void* d_ws, size_t ws_size,
                              hipStream_t stream) {
    const float* x = (const float*)d_in[0];
    const float* v = (const float*)d_in[1];
    float* y = (float*)d_out;
    const int nrows = in_sizes[0] / 128;

    const int block = 256;
    const int groups_per_block = 16;
    const int n_chunks = nrows / 2;
    int grid = (n_chunks + groups_per_block - 1) / groups_per_block;
    if (grid > 2048) grid = 2048;
    if (grid < 1) grid = 1;

    hh_kernel<<<grid, block, 0, stream>>>(x, v, y, nrows);
}

// Round 6
// 358.679 us; speedup vs baseline: 1.1364x; 1.0703x over previous
//
#include <hip/hip_runtime.h>

typedef float f32x4 __attribute__((ext_vector_type(4)));

// DPP-based add with compile-time ctrl (row_mask=0xF, bank_mask=0xF, bound_ctrl=1)
template<int CTRL>
__device__ __forceinline__ float dpp_add(float x) {
    int y = __builtin_amdgcn_update_dpp(0, __float_as_int(x), CTRL, 0xF, 0xF, true);
    return x + __int_as_float(y);
}

// Sum across a 16-lane group, result in all 16 lanes. Pure VALU (no DS pipe).
__device__ __forceinline__ float reduce16(float x) {
    x = dpp_add<0xB1>(x);   // quad_perm [1,0,3,2]
    x = dpp_add<0x4E>(x);   // quad_perm [2,3,0,1]
    x = dpp_add<0x141>(x);  // row_half_mirror
    x = dpp_add<0x140>(x);  // row_mirror
    return x;
}

__device__ __forceinline__ float dot4(f32x4 a, f32x4 b) {
    return a.x * b.x + a.y * b.y + a.z * b.z + a.w * b.w;
}

// y[b,:] = x[b,:] - (2 * dot(x[b],v) / ||v||^2) * v
// D = 128 floats/row. 16 lanes/row, 2 float4/lane; ONE 2-row chunk per group
// (flat launch: no grid-stride loop, block turnover provides stream overlap).
__global__ __launch_bounds__(256) void hh_kernel(const float* __restrict__ x,
                                                 const float* __restrict__ v,
                                                 float* __restrict__ y,
                                                 int nrows) {
    const int tid = threadIdx.x;
    const int c = tid & 15;   // float4 slot within row-half
    const int g = tid >> 4;   // 16-lane group within block (0..15)

    const f32x4* vv = reinterpret_cast<const f32x4*>(v);
    const f32x4 vA = vv[c];
    const f32x4 vB = vv[c + 16];

    const float p = reduce16(dot4(vA, vA) + dot4(vB, vB));
    const float scale = 2.0f / p;

    const int n_chunks = nrows >> 1;  // chunks of 2 consecutive rows
    const int chunk = blockIdx.x * 16 + g;

    if (chunk < n_chunks) {
        const f32x4* xp = reinterpret_cast<const f32x4*>(x + (size_t)chunk * 256);
        f32x4* yp = reinterpret_cast<f32x4*>(y + (size_t)chunk * 256);

        const f32x4 a0A = __builtin_nontemporal_load(xp + c);
        const f32x4 a0B = __builtin_nontemporal_load(xp + c + 16);
        const f32x4 a1A = __builtin_nontemporal_load(xp + c + 32);
        const f32x4 a1B = __builtin_nontemporal_load(xp + c + 48);

        float d0 = reduce16(dot4(a0A, vA) + dot4(a0B, vB));
        float d1 = reduce16(dot4(a1A, vA) + dot4(a1B, vB));
        const float s0 = scale * d0;
        const float s1 = scale * d1;

        f32x4 o;
        o.x = a0A.x - s0 * vA.x; o.y = a0A.y - s0 * vA.y; o.z = a0A.z - s0 * vA.z; o.w = a0A.w - s0 * vA.w;
        __builtin_nontemporal_store(o, yp + c);
        o.x = a0B.x - s0 * vB.x; o.y = a0B.y - s0 * vB.y; o.z = a0B.z - s0 * vB.z; o.w = a0B.w - s0 * vB.w;
        __builtin_nontemporal_store(o, yp + c + 16);
        o.x = a1A.x - s1 * vA.x; o.y = a1A.y - s1 * vA.y; o.z = a1A.z - s1 * vA.z; o.w = a1A.w - s1 * vA.w;
        __builtin_nontemporal_store(o, yp + c + 32);
        o.x = a1B.x - s1 * vB.x; o.y = a1B.y - s1 * vB.y; o.z = a1B.z - s1 * vB.z; o.w = a1B.w - s1 * vB.w;
        __builtin_nontemporal_store(o, yp + c + 48);
    }

    // tail row if nrows is odd (not hit for B = 2^21, kept for safety)
    if (blockIdx.x == 0 && g == 0) {
        for (int row = n_chunks << 1; row < nrows; ++row) {
            const f32x4* xp = reinterpret_cast<const f32x4*>(x + (size_t)row * 128);
            f32x4* yp = reinterpret_cast<f32x4*>(y + (size_t)row * 128);
            const f32x4 aA = xp[c];
            const f32x4 aB = xp[c + 16];
            const float s = scale * reduce16(dot4(aA, vA) + dot4(aB, vB));
            f32x4 o;
            o.x = aA.x - s * vA.x; o.y = aA.y - s * vA.y; o.z = aA.z - s * vA.z; o.w = aA.w - s * vA.w;
            yp[c] = o;
            o.x = aB.x - s * vB.x; o.y = aB.y - s * vB.y; o.z = aB.z - s * vB.z; o.w = aB.w - s * vB.w;
            yp[c + 16] = o;
        }
    }

    // second tuple output: scalar 0 after y
    if (blockIdx.x == 0 && tid == 0) y[(size_t)nrows * 128] = 0.0f;
}

extern "C" void kernel_launch(void* const* d_in, const int* in_sizes, int n_in,
                              void* d_out, int out_size, void* d_ws, size_t ws_size,
                              hipStream_t stream) {
    const float* x = (const float*)d_in[0];
    const float* v = (const float*)d_in[1];
    float* y = (float*)d_out;
    const int nrows = in_sizes[0] / 128;

    const int block = 256;
    const int groups_per_block = 16;
    const int n_chunks = nrows / 2;
    int grid = (n_chunks + groups_per_block - 1) / groups_per_block;  // flat: 1 chunk/group
    if (grid < 1) grid = 1;

    hh_kernel<<<grid, block, 0, stream>>>(x, v, y, nrows);
}